// Round 5
// baseline (1531.674 us; speedup 1.0000x reference)
//
#include <hip/hip_runtime.h>
#include <hip/hip_bf16.h>
#include <cstdint>

// Sparse top-2 MoE (DBRX experts), MI355X gfx950.
// router -> scan -> assign -> V = X v1^T -> H = silu(X w1^T) * V (fused epilogue, in place)
//   -> outslot = gate * (H w2^T) -> combine.
// GEMM: 128x128x64 tiles, 256 thr (4 waves, 2Mx2N, 64x64/wave), mfma 16x16x32 bf16.
// Structure (R1-proven TLP regime: 48.5 KB LDS -> 3 blocks/CU = 12 waves/CU):
//   per K-tile t: [pb holds B(t); As[t&1] holds A(t), drained]
//     cvt pb -> ds_write Bs (XOR-swizzled)
//     __syncthreads()                     // implicit vmcnt(0): drains A(t) gload; publishes Bs
//     issue gload_lds A(t+1) -> As[(t+1)&1]; load B(t+1) fp32 -> pb   // full-tile windows
//     MFMA(t)
//     lgkmcnt(0); raw s_barrier           // orders LDS reads vs next writes; vmem stays in flight
//   Race proof: Bs write(t+1) after raw-bar(t) > all reads(t). As[(t+1)&1] gload issued after
//   sync(t) > reads(t-1) done at raw-bar(t-1). A(t+1) drained by sync(t+1) before MFMA(t+1).

#define T_TOK 4096
#define DHID  2048
#define NEXP  8
#define IDIM  4096
#define NSLOT (T_TOK * 2)

#define BM 128
#define BN 128
#define BK 64

typedef __bf16 bf16x8 __attribute__((ext_vector_type(8)));
typedef __bf16 bf16x4 __attribute__((ext_vector_type(4)));
typedef float  f32x4  __attribute__((ext_vector_type(4)));

__device__ __forceinline__ void gload_lds16(const void* g, void* l) {
    __builtin_amdgcn_global_load_lds(
        (const __attribute__((address_space(1))) uint32_t*)g,
        (__attribute__((address_space(3))) uint32_t*)l, 16, 0, 0);
}

// ---------------- router ----------------
__global__ __launch_bounds__(256) void router_kernel(
    const float* __restrict__ x, const float* __restrict__ wr,
    __bf16* __restrict__ xb, int* __restrict__ topi, float* __restrict__ topg,
    int* __restrict__ cnt)
{
    int wave = threadIdx.x >> 6, lane = threadIdx.x & 63;
    int t = blockIdx.x * 4 + wave;
    const float4* xr = (const float4*)(x + (size_t)t * DHID);
    bf16x4* xbo = (bf16x4*)(xb + (size_t)t * DHID);
    float acc[NEXP];
#pragma unroll
    for (int e = 0; e < NEXP; ++e) acc[e] = 0.f;
#pragma unroll
    for (int j = 0; j < DHID / 256; ++j) {
        int d4 = lane + j * 64;
        float4 v = xr[d4];
        bf16x4 bv;
        bv[0] = (__bf16)v.x; bv[1] = (__bf16)v.y;
        bv[2] = (__bf16)v.z; bv[3] = (__bf16)v.w;
        xbo[d4] = bv;
#pragma unroll
        for (int e = 0; e < NEXP; ++e) {
            float4 w = ((const float4*)(wr + e * DHID))[d4];
            acc[e] += v.x * w.x + v.y * w.y + v.z * w.z + v.w * w.w;
        }
    }
#pragma unroll
    for (int e = 0; e < NEXP; ++e) {
#pragma unroll
        for (int s = 32; s > 0; s >>= 1) acc[e] += __shfl_xor(acc[e], s);
    }
    if (lane == 0) {
        int e0 = 0; float l0 = acc[0];
#pragma unroll
        for (int e = 1; e < NEXP; ++e) if (acc[e] > l0) { l0 = acc[e]; e0 = e; }
        int e1 = -1; float l1 = -3.4e38f;
#pragma unroll
        for (int e = 0; e < NEXP; ++e) if (e != e0 && acc[e] > l1) { l1 = acc[e]; e1 = e; }
        float g0 = 1.f / (1.f + __expf(l1 - l0));
        topi[t * 2] = e0; topi[t * 2 + 1] = e1;
        topg[t * 2] = g0; topg[t * 2 + 1] = 1.f - g0;
        atomicAdd(&cnt[e0], 1); atomicAdd(&cnt[e1], 1);
    }
}

__global__ void scan_kernel(const int* __restrict__ cnt, int* __restrict__ basep,
                            int* __restrict__ fill)
{
    if (threadIdx.x == 0 && blockIdx.x == 0) {
        int s = 0;
#pragma unroll
        for (int e = 0; e < NEXP; ++e) { basep[e] = s; s += cnt[e]; fill[e] = 0; }
    }
}

__global__ __launch_bounds__(256) void assign_kernel(
    const int* __restrict__ topi, const float* __restrict__ topg,
    const int* __restrict__ basep, int* __restrict__ fill,
    int* __restrict__ tok_of_slot, float* __restrict__ gate_of_slot,
    int* __restrict__ slot_of)
{
    int t = blockIdx.x * 256 + threadIdx.x;
    if (t >= T_TOK) return;
#pragma unroll
    for (int k = 0; k < 2; ++k) {
        int e = topi[t * 2 + k];
        int slot = basep[e] + atomicAdd(&fill[e], 1);
        tok_of_slot[slot] = t;
        gate_of_slot[slot] = topg[t * 2 + k];
        slot_of[t * 2 + k] = slot;
    }
}

// ---------------- GEMM pass ----------------
// PASS 1 (V):    Out = A W^T                      A=xb gather, W=v1[e], Out=V
// PASS 2 (U+glu):Out = silu(A W^T) * Vread        A=xb gather, W=w1[e], Out=V (in place)
// PASS 3 (down): Out = gate * (A W^T)             A=H contig,  W=w2[e], Out=outslot
template <int PASS, int KDIM>
__global__ __launch_bounds__(256, 3) void moe_gemm(
    const __bf16* __restrict__ Abase, const float* __restrict__ W,
    const int* __restrict__ tok_of_slot, const float* __restrict__ gate_of_slot,
    const int* __restrict__ cnt, const int* __restrict__ basep,
    __bf16* Out, const __bf16* Vread, int ostride)
{
    int e  = blockIdx.z;
    int ne = cnt[e];
    int m0 = blockIdx.y * BM;
    if (m0 >= ne) return;
    int n0 = blockIdx.x * BN;
    int sbase = basep[e] + m0;

    __shared__ __bf16 As[2][BM * BK];   // 2 x 16 KiB
    __shared__ __bf16 Bs[BM * BK];      // 16 KiB
    __shared__ int toks[BM];

    int tid = threadIdx.x, lane = tid & 63, wave = tid >> 6;
    char* AsB = (char*)&As[0][0];
    char* BsB = (char*)&Bs[0];

    if (PASS < 3) {
        if (tid < BM) toks[tid] = (m0 + tid < ne) ? tok_of_slot[sbase + tid] : 0;
        __syncthreads();
    }

    // A staging: 16 chunks of 1 KiB (wave-uniform dest), 4 gload_lds(16B)/thread.
    // Linear LDS dest; source col-chunk pre-swizzled so swizzled reads decode.
    const __bf16* a_src[4];
    int a_coff[4];
#pragma unroll
    for (int r = 0; r < 4; ++r) {
        int chunk = wave * 4 + r;
        int arow  = chunk * 8 + (lane >> 3);
        int csw   = (lane & 7) ^ (arow & 7);
        size_t rowbase;
        if (PASS < 3) {
            rowbase = (size_t)toks[arow] * KDIM;
        } else {
            int srow = (m0 + arow < ne) ? (sbase + arow) : sbase;
            rowbase = (size_t)srow * KDIM;
        }
        a_src[r]  = Abase + rowbase + csw * 8;
        a_coff[r] = chunk * 1024;
    }

    // B staging: row = tid>>1, half = tid&1 (32 floats = 8 float4 per thread).
    int brow = tid >> 1, bh = tid & 1;
    const float* b_src = W + (size_t)e * ((size_t)KDIM * (PASS == 3 ? DHID : IDIM))
                         + (size_t)(n0 + brow) * KDIM + bh * 32;
    int b_woff[4];
#pragma unroll
    for (int j = 0; j < 4; ++j)
        b_woff[j] = brow * 128 + ((bh * 64 + j * 16) ^ ((brow & 7) << 4));

    int wr0 = (wave >> 1) * 64, wc0 = (wave & 1) * 64;

    f32x4 acc[4][4];
    f32x4 zf = {0.f, 0.f, 0.f, 0.f};
#pragma unroll
    for (int m = 0; m < 4; ++m)
#pragma unroll
        for (int n = 0; n < 4; ++n) acc[m][n] = zf;

    float4 pb[8];
    const int NK = KDIM / BK;

    // prologue: A(0) -> As[0], B(0) -> pb
#pragma unroll
    for (int r = 0; r < 4; ++r) gload_lds16(a_src[r], AsB + a_coff[r]);
#pragma unroll
    for (int j = 0; j < 8; ++j) pb[j] = *(const float4*)(b_src + j * 4);

    for (int t = 0; t < NK; ++t) {
        int cur = t & 1;
        // publish B(t): cvt + XOR-swizzled ds_write (single Bs buffer)
#pragma unroll
        for (int j = 0; j < 4; ++j) {
            float4 fa = pb[2 * j], fb = pb[2 * j + 1];
            bf16x8 bv;
            bv[0]=(__bf16)fa.x; bv[1]=(__bf16)fa.y; bv[2]=(__bf16)fa.z; bv[3]=(__bf16)fa.w;
            bv[4]=(__bf16)fb.x; bv[5]=(__bf16)fb.y; bv[6]=(__bf16)fb.z; bv[7]=(__bf16)fb.w;
            *(bf16x8*)(BsB + b_woff[j]) = bv;
        }
        __syncthreads();   // drains A(t) gload (implicit vmcnt 0) + publishes Bs/As
        // issue next tile's loads (full-tile latency windows)
        if (t + 1 < NK) {
            const float* bs = b_src + (size_t)(t + 1) * BK;
#pragma unroll
            for (int r = 0; r < 4; ++r)
                gload_lds16(a_src[r] + (size_t)(t + 1) * BK, AsB + (cur ^ 1) * 16384 + a_coff[r]);
#pragma unroll
            for (int j = 0; j < 8; ++j) pb[j] = *(const float4*)(bs + j * 4);
        }
        // compute tile t
        __builtin_amdgcn_s_setprio(1);
#pragma unroll
        for (int ks = 0; ks < 2; ++ks) {
            int kb = ks * 64 + (lane >> 4) * 16;
            bf16x8 af[4], bfr[4];
#pragma unroll
            for (int m = 0; m < 4; ++m) {
                int row = wr0 + m * 16 + (lane & 15);
                af[m] = *(const bf16x8*)(AsB + cur * 16384 + row * 128 + (kb ^ ((row & 7) << 4)));
            }
#pragma unroll
            for (int n = 0; n < 4; ++n) {
                int row = wc0 + n * 16 + (lane & 15);
                bfr[n] = *(const bf16x8*)(BsB + row * 128 + (kb ^ ((row & 7) << 4)));
            }
#pragma unroll
            for (int m = 0; m < 4; ++m)
#pragma unroll
                for (int n = 0; n < 4; ++n)
                    acc[m][n] = __builtin_amdgcn_mfma_f32_16x16x32_bf16(af[m], bfr[n], acc[m][n], 0, 0, 0);
        }
        __builtin_amdgcn_s_setprio(0);
        if (t + 1 < NK) {
            // order LDS reads before next tile's writes; vmem stays in flight
            asm volatile("s_waitcnt lgkmcnt(0)" ::: "memory");
            __builtin_amdgcn_s_barrier();
            asm volatile("" ::: "memory");
        }
    }

    // epilogue
#pragma unroll
    for (int m = 0; m < 4; ++m) {
        int rbase = wr0 + m * 16 + ((lane >> 4) * 4);
#pragma unroll
        for (int n = 0; n < 4; ++n) {
            int col = n0 + wc0 + n * 16 + (lane & 15);
#pragma unroll
            for (int r = 0; r < 4; ++r) {
                int lrow = rbase + r;
                if (m0 + lrow < ne) {
                    size_t oidx = (size_t)(sbase + lrow) * ostride + col;
                    float v = acc[m][n][r];
                    if (PASS == 2) {
                        v = (v / (1.f + __expf(-v))) * (float)Vread[oidx];
                    } else if (PASS == 3) {
                        v *= gate_of_slot[sbase + lrow];
                    }
                    Out[oidx] = (__bf16)v;
                }
            }
        }
    }
}

// ---------------- combine ----------------
__global__ __launch_bounds__(256) void combine_kernel(
    const __bf16* __restrict__ outslot, const int* __restrict__ slot_of,
    float* __restrict__ out)
{
    int idx = blockIdx.x * 256 + threadIdx.x;
    int t = idx >> 8;
    int c = (idx & 255) * 8;
    int s0 = slot_of[t * 2], s1 = slot_of[t * 2 + 1];
    bf16x8 a = *(const bf16x8*)(outslot + (size_t)s0 * DHID + c);
    bf16x8 b = *(const bf16x8*)(outslot + (size_t)s1 * DHID + c);
    float4 o0, o1;
    o0.x = (float)a[0] + (float)b[0];
    o0.y = (float)a[1] + (float)b[1];
    o0.z = (float)a[2] + (float)b[2];
    o0.w = (float)a[3] + (float)b[3];
    o1.x = (float)a[4] + (float)b[4];
    o1.y = (float)a[5] + (float)b[5];
    o1.z = (float)a[6] + (float)b[6];
    o1.w = (float)a[7] + (float)b[7];
    *(float4*)(out + (size_t)t * DHID + c)     = o0;
    *(float4*)(out + (size_t)t * DHID + c + 4) = o1;
}

extern "C" void kernel_launch(void* const* d_in, const int* in_sizes, int n_in,
                              void* d_out, int out_size, void* d_ws, size_t ws_size,
                              hipStream_t stream)
{
    (void)in_sizes; (void)n_in; (void)out_size; (void)ws_size;
    const float* x  = (const float*)d_in[0];
    const float* wr = (const float*)d_in[1];
    const float* w1 = (const float*)d_in[2];
    const float* v1 = (const float*)d_in[3];
    const float* w2 = (const float*)d_in[4];
    float* out = (float*)d_out;

    char* ws = (char*)d_ws;
    size_t off = 0;
    auto alloc = [&](size_t bytes) -> void* {
        void* p = ws + off;
        off += bytes;
        off = (off + 255) & ~(size_t)255;
        return p;
    };
    __bf16* xb      = (__bf16*)alloc((size_t)T_TOK * DHID * 2);
    __bf16* V       = (__bf16*)alloc((size_t)NSLOT * IDIM * 2);   // V, then H in place
    __bf16* outslot = (__bf16*)alloc((size_t)NSLOT * DHID * 2);
    int*    topi    = (int*)  alloc((size_t)T_TOK * 2 * 4);
    float*  topg    = (float*)alloc((size_t)T_TOK * 2 * 4);
    int*    tok_of_slot  = (int*)  alloc((size_t)NSLOT * 4);
    float*  gate_of_slot = (float*)alloc((size_t)NSLOT * 4);
    int*    slot_of = (int*)  alloc((size_t)NSLOT * 4);
    int*    cnt     = (int*)  alloc(NEXP * 4);
    int*    basep   = (int*)  alloc(NEXP * 4);
    int*    fill    = (int*)  alloc(NEXP * 4);

    hipMemsetAsync(cnt, 0, NEXP * 4, stream);
    router_kernel<<<T_TOK / 4, 256, 0, stream>>>(x, wr, xb, topi, topg, cnt);
    scan_kernel<<<1, 64, 0, stream>>>(cnt, basep, fill);
    assign_kernel<<<T_TOK / 256, 256, 0, stream>>>(topi, topg, basep, fill,
                                                   tok_of_slot, gate_of_slot, slot_of);
    // V = X v1^T
    moe_gemm<1, DHID><<<dim3(IDIM / BN, T_TOK / BM, NEXP), 256, 0, stream>>>(
        xb, v1, tok_of_slot, gate_of_slot, cnt, basep, V, nullptr, IDIM);
    // H = silu(X w1^T) * V   (in place over V)
    moe_gemm<2, DHID><<<dim3(IDIM / BN, T_TOK / BM, NEXP), 256, 0, stream>>>(
        xb, w1, tok_of_slot, gate_of_slot, cnt, basep, V, V, IDIM);
    // outslot = gate * (H w2^T)
    moe_gemm<3, IDIM><<<dim3(DHID / BN, T_TOK / BM, NEXP), 256, 0, stream>>>(
        V, w2, tok_of_slot, gate_of_slot, cnt, basep, outslot, nullptr, DHID);
    combine_kernel<<<(T_TOK * DHID / 8) / 256, 256, 0, stream>>>(outslot, slot_of, out);
}

// Round 6
// 905.551 us; speedup vs baseline: 1.6914x; 1.6914x over previous
//
#include <hip/hip_runtime.h>
#include <hip/hip_bf16.h>
#include <cstdint>

// Sparse top-2 MoE (DBRX experts), MI355X gfx950.
// router -> scan -> assign -> cvt(w1,v1 -> bf16) -> proj dual-B (H = silu(X w1^T)*(X v1^T))
//   -> cvt(w2 -> bf16, aliased over wb1/wv1) -> down dual-N (outslot = gate*(H w2^T)) -> combine.
// GEMM skeleton = R1's empirically-best regime: 128-row tiles, 256 thr (4 waves, 2Mx2N),
// single-buffered LDS, TWO __syncthreads per K-tile, fully synchronous staging; latency
// hidden by thread-level parallelism (2 blocks/CU). The round-6 change: ALL tiles are bf16
// and staged direct via global_load_lds (no fp32 reg round-trip, half the weight bytes).
// Dual-B/dual-N: each stall services 256 MFMAs instead of 128.

#define T_TOK 4096
#define DHID  2048
#define NEXP  8
#define IDIM  4096
#define NSLOT (T_TOK * 2)

#define BM 128
#define BK 64

typedef __bf16 bf16x8 __attribute__((ext_vector_type(8)));
typedef __bf16 bf16x4 __attribute__((ext_vector_type(4)));
typedef float  f32x4  __attribute__((ext_vector_type(4)));

__device__ __forceinline__ void gload_lds16(const void* g, void* l) {
    __builtin_amdgcn_global_load_lds(
        (const __attribute__((address_space(1))) uint32_t*)g,
        (__attribute__((address_space(3))) uint32_t*)l, 16, 0, 0);
}

// ---------------- router ----------------
__global__ __launch_bounds__(256) void router_kernel(
    const float* __restrict__ x, const float* __restrict__ wr,
    __bf16* __restrict__ xb, int* __restrict__ topi, float* __restrict__ topg,
    int* __restrict__ cnt)
{
    int wave = threadIdx.x >> 6, lane = threadIdx.x & 63;
    int t = blockIdx.x * 4 + wave;
    const float4* xr = (const float4*)(x + (size_t)t * DHID);
    bf16x4* xbo = (bf16x4*)(xb + (size_t)t * DHID);
    float acc[NEXP];
#pragma unroll
    for (int e = 0; e < NEXP; ++e) acc[e] = 0.f;
#pragma unroll
    for (int j = 0; j < DHID / 256; ++j) {
        int d4 = lane + j * 64;
        float4 v = xr[d4];
        bf16x4 bv;
        bv[0] = (__bf16)v.x; bv[1] = (__bf16)v.y;
        bv[2] = (__bf16)v.z; bv[3] = (__bf16)v.w;
        xbo[d4] = bv;
#pragma unroll
        for (int e = 0; e < NEXP; ++e) {
            float4 w = ((const float4*)(wr + e * DHID))[d4];
            acc[e] += v.x * w.x + v.y * w.y + v.z * w.z + v.w * w.w;
        }
    }
#pragma unroll
    for (int e = 0; e < NEXP; ++e) {
#pragma unroll
        for (int s = 32; s > 0; s >>= 1) acc[e] += __shfl_xor(acc[e], s);
    }
    if (lane == 0) {
        int e0 = 0; float l0 = acc[0];
#pragma unroll
        for (int e = 1; e < NEXP; ++e) if (acc[e] > l0) { l0 = acc[e]; e0 = e; }
        int e1 = -1; float l1 = -3.4e38f;
#pragma unroll
        for (int e = 0; e < NEXP; ++e) if (e != e0 && acc[e] > l1) { l1 = acc[e]; e1 = e; }
        float g0 = 1.f / (1.f + __expf(l1 - l0));
        topi[t * 2] = e0; topi[t * 2 + 1] = e1;
        topg[t * 2] = g0; topg[t * 2 + 1] = 1.f - g0;
        atomicAdd(&cnt[e0], 1); atomicAdd(&cnt[e1], 1);
    }
}

__global__ void scan_kernel(const int* __restrict__ cnt, int* __restrict__ basep,
                            int* __restrict__ fill)
{
    if (threadIdx.x == 0 && blockIdx.x == 0) {
        int s = 0;
#pragma unroll
        for (int e = 0; e < NEXP; ++e) { basep[e] = s; s += cnt[e]; fill[e] = 0; }
    }
}

__global__ __launch_bounds__(256) void assign_kernel(
    const int* __restrict__ topi, const float* __restrict__ topg,
    const int* __restrict__ basep, int* __restrict__ fill,
    int* __restrict__ tok_of_slot, float* __restrict__ gate_of_slot,
    int* __restrict__ slot_of)
{
    int t = blockIdx.x * 256 + threadIdx.x;
    if (t >= T_TOK) return;
#pragma unroll
    for (int k = 0; k < 2; ++k) {
        int e = topi[t * 2 + k];
        int slot = basep[e] + atomicAdd(&fill[e], 1);
        tok_of_slot[slot] = t;
        gate_of_slot[slot] = topg[t * 2 + k];
        slot_of[t * 2 + k] = slot;
    }
}

// ---------------- fp32 -> bf16 weight convert ----------------
__global__ __launch_bounds__(256) void convert_kernel(
    const float* __restrict__ src, __bf16* __restrict__ dst, size_t n8)
{
    for (size_t i = (size_t)blockIdx.x * 256 + threadIdx.x; i < n8;
         i += (size_t)gridDim.x * 256) {
        const float4* s = (const float4*)(src + i * 8);
        float4 a = s[0], b = s[1];
        bf16x8 o;
        o[0]=(__bf16)a.x; o[1]=(__bf16)a.y; o[2]=(__bf16)a.z; o[3]=(__bf16)a.w;
        o[4]=(__bf16)b.x; o[5]=(__bf16)b.y; o[6]=(__bf16)b.z; o[7]=(__bf16)b.w;
        *(bf16x8*)(dst + i * 8) = o;
    }
}

// ---------------- dual GEMM (R1 skeleton) ----------------
// PASS 1 (proj): acc1 = X w1^T, acc2 = X v1^T over the SAME 128x128 (m,n) tile;
//                epilogue H = silu(acc1)*acc2. A=xb gather; n0 = bx*128.
// PASS 2 (down): dual-N: acc1 = H w2[n0..n0+128)^T, acc2 = H w2[n0+128..n0+256)^T;
//                epilogue outslot = gate*acc. A=H contig; n0 = bx*256.
// BF16B=true: B1/B2 staged via global_load_lds from pre-converted bf16 weights.
// BF16B=false (ws fallback): B1/B2 fp32 -> regs -> cvt -> swizzled ds_write.
template <int PASS, int KDIM, bool BF16B>
__global__ __launch_bounds__(256, 2) void moe_gemm(
    const __bf16* __restrict__ Abase,
    const void* __restrict__ WaV, const void* __restrict__ WbV,
    const int* __restrict__ tok_of_slot, const float* __restrict__ gate_of_slot,
    const int* __restrict__ cnt, const int* __restrict__ basep,
    __bf16* __restrict__ Out)
{
    int e  = blockIdx.z;
    int ne = cnt[e];
    int m0 = blockIdx.y * BM;
    if (m0 >= ne) return;
    int n0 = blockIdx.x * (PASS == 1 ? 128 : 256);
    int sbase = basep[e] + m0;

    __shared__ __bf16 As[BM * BK];    // 16 KiB
    __shared__ __bf16 B1s[BM * BK];   // 16 KiB
    __shared__ __bf16 B2s[BM * BK];   // 16 KiB
    __shared__ int   toks[BM];
    __shared__ float gates[BM];

    int tid = threadIdx.x, lane = tid & 63, wave = tid >> 6;
    char* AsB = (char*)&As[0];
    char* B1B = (char*)&B1s[0];
    char* B2B = (char*)&B2s[0];

    if (PASS == 1) {
        if (tid < BM) toks[tid] = (m0 + tid < ne) ? tok_of_slot[sbase + tid] : 0;
    } else {
        if (tid < BM) gates[tid] = gate_of_slot[(m0 + tid < ne) ? (sbase + tid) : sbase];
    }
    __syncthreads();

    // ---- A staging: 16 chunks of 1 KiB (wave-uniform dest), 4 gload_lds(16B)/thread.
    // Linear LDS dest + pre-swizzled global source column-chunk (rule #21).
    const __bf16* a_src[4];
    int coff[4];
#pragma unroll
    for (int r = 0; r < 4; ++r) {
        int chunk = wave * 4 + r;
        int arow  = chunk * 8 + (lane >> 3);
        int csw   = (lane & 7) ^ (arow & 7);
        size_t rowbase;
        if (PASS == 1) {
            rowbase = (size_t)toks[arow] * KDIM;
        } else {
            int srow = (m0 + arow < ne) ? (sbase + arow) : sbase;
            rowbase = (size_t)srow * KDIM;
        }
        a_src[r] = Abase + rowbase + csw * 8;
        coff[r]  = chunk * 1024;
    }

    // ---- B staging setup
    const __bf16* b1_src[4];
    const __bf16* b2_src[4];
    const float *f1_src = nullptr, *f2_src = nullptr;
    int b_woff[4];
    if constexpr (BF16B) {
        const __bf16* Wae;
        const __bf16* Wbe;
        if (PASS == 1) {
            Wae = (const __bf16*)WaV + (size_t)e * IDIM * DHID;
            Wbe = (const __bf16*)WbV + (size_t)e * IDIM * DHID;
        } else {
            Wae = (const __bf16*)WaV + (size_t)e * DHID * IDIM;
            Wbe = Wae + (size_t)128 * KDIM;
        }
#pragma unroll
        for (int r = 0; r < 4; ++r) {
            int chunk = wave * 4 + r;
            int brow  = chunk * 8 + (lane >> 3);
            int csw   = (lane & 7) ^ (brow & 7);
            b1_src[r] = Wae + (size_t)(n0 + brow) * KDIM + csw * 8;
            b2_src[r] = Wbe + (size_t)(n0 + brow) * KDIM + csw * 8;
        }
    } else {
        const float* Wae;
        const float* Wbe;
        if (PASS == 1) {
            Wae = (const float*)WaV + (size_t)e * IDIM * DHID;
            Wbe = (const float*)WbV + (size_t)e * IDIM * DHID;
        } else {
            Wae = (const float*)WaV + (size_t)e * DHID * IDIM;
            Wbe = Wae + (size_t)128 * KDIM;
        }
        int brow = tid >> 1, bh = tid & 1;
        f1_src = Wae + (size_t)(n0 + brow) * KDIM + bh * 32;
        f2_src = Wbe + (size_t)(n0 + brow) * KDIM + bh * 32;
#pragma unroll
        for (int j = 0; j < 4; ++j)
            b_woff[j] = brow * 128 + ((bh * 64 + j * 16) ^ ((brow & 7) << 4));
    }

    int wr0 = (wave >> 1) * 64, wc0 = (wave & 1) * 64;

    f32x4 acc1[4][4], acc2[4][4];
    f32x4 zf = {0.f, 0.f, 0.f, 0.f};
#pragma unroll
    for (int m = 0; m < 4; ++m)
#pragma unroll
        for (int n = 0; n < 4; ++n) { acc1[m][n] = zf; acc2[m][n] = zf; }

    const int NK = KDIM / BK;
    for (int t = 0; t < NK; ++t) {
        int ko = t * BK;
        // stage tile t (synchronous; TLP hides the latency)
#pragma unroll
        for (int r = 0; r < 4; ++r) gload_lds16(a_src[r] + ko, AsB + coff[r]);
        if constexpr (BF16B) {
#pragma unroll
            for (int r = 0; r < 4; ++r) gload_lds16(b1_src[r] + ko, B1B + coff[r]);
#pragma unroll
            for (int r = 0; r < 4; ++r) gload_lds16(b2_src[r] + ko, B2B + coff[r]);
        } else {
            {
                float4 q[8];
#pragma unroll
                for (int j = 0; j < 8; ++j) q[j] = *(const float4*)(f1_src + ko + j * 4);
#pragma unroll
                for (int j = 0; j < 4; ++j) {
                    float4 fa = q[2 * j], fb = q[2 * j + 1];
                    bf16x8 bv;
                    bv[0]=(__bf16)fa.x; bv[1]=(__bf16)fa.y; bv[2]=(__bf16)fa.z; bv[3]=(__bf16)fa.w;
                    bv[4]=(__bf16)fb.x; bv[5]=(__bf16)fb.y; bv[6]=(__bf16)fb.z; bv[7]=(__bf16)fb.w;
                    *(bf16x8*)(B1B + b_woff[j]) = bv;
                }
            }
            {
                float4 q[8];
#pragma unroll
                for (int j = 0; j < 8; ++j) q[j] = *(const float4*)(f2_src + ko + j * 4);
#pragma unroll
                for (int j = 0; j < 4; ++j) {
                    float4 fa = q[2 * j], fb = q[2 * j + 1];
                    bf16x8 bv;
                    bv[0]=(__bf16)fa.x; bv[1]=(__bf16)fa.y; bv[2]=(__bf16)fa.z; bv[3]=(__bf16)fa.w;
                    bv[4]=(__bf16)fb.x; bv[5]=(__bf16)fb.y; bv[6]=(__bf16)fb.z; bv[7]=(__bf16)fb.w;
                    *(bf16x8*)(B2B + b_woff[j]) = bv;
                }
            }
        }
        __syncthreads();   // drains gload_lds (implicit vmcnt 0) + publishes LDS
        // compute tile t: 256 MFMAs per block (dual)
#pragma unroll
        for (int ks = 0; ks < 2; ++ks) {
            int kb = ks * 64 + (lane >> 4) * 16;
            bf16x8 af[4], b1f[4], b2f[4];
#pragma unroll
            for (int m = 0; m < 4; ++m) {
                int row = wr0 + m * 16 + (lane & 15);
                af[m] = *(const bf16x8*)(AsB + row * 128 + (kb ^ ((row & 7) << 4)));
            }
#pragma unroll
            for (int n = 0; n < 4; ++n) {
                int row = wc0 + n * 16 + (lane & 15);
                int off = row * 128 + (kb ^ ((row & 7) << 4));
                b1f[n] = *(const bf16x8*)(B1B + off);
                b2f[n] = *(const bf16x8*)(B2B + off);
            }
#pragma unroll
            for (int m = 0; m < 4; ++m)
#pragma unroll
                for (int n = 0; n < 4; ++n) {
                    acc1[m][n] = __builtin_amdgcn_mfma_f32_16x16x32_bf16(af[m], b1f[n], acc1[m][n], 0, 0, 0);
                    acc2[m][n] = __builtin_amdgcn_mfma_f32_16x16x32_bf16(af[m], b2f[n], acc2[m][n], 0, 0, 0);
                }
        }
        __syncthreads();   // reads done before next tile's staging writes
    }

    // ---- epilogue
#pragma unroll
    for (int m = 0; m < 4; ++m) {
        int rbase = wr0 + m * 16 + ((lane >> 4) * 4);
#pragma unroll
        for (int n = 0; n < 4; ++n) {
            int col = wc0 + n * 16 + (lane & 15);
#pragma unroll
            for (int r = 0; r < 4; ++r) {
                int lrow = rbase + r;
                if (m0 + lrow < ne) {
                    if (PASS == 1) {
                        float a = acc1[m][n][r];
                        float b = acc2[m][n][r];
                        float h = (a / (1.f + __expf(-a))) * b;
                        Out[(size_t)(sbase + lrow) * IDIM + n0 + col] = (__bf16)h;
                    } else {
                        float g = gates[lrow];
                        size_t obase = (size_t)(sbase + lrow) * DHID + n0;
                        Out[obase + col]       = (__bf16)(acc1[m][n][r] * g);
                        Out[obase + 128 + col] = (__bf16)(acc2[m][n][r] * g);
                    }
                }
            }
        }
    }
}

// ---------------- combine ----------------
__global__ __launch_bounds__(256) void combine_kernel(
    const __bf16* __restrict__ outslot, const int* __restrict__ slot_of,
    float* __restrict__ out)
{
    int idx = blockIdx.x * 256 + threadIdx.x;
    int t = idx >> 8;
    int c = (idx & 255) * 8;
    int s0 = slot_of[t * 2], s1 = slot_of[t * 2 + 1];
    bf16x8 a = *(const bf16x8*)(outslot + (size_t)s0 * DHID + c);
    bf16x8 b = *(const bf16x8*)(outslot + (size_t)s1 * DHID + c);
    float4 o0, o1;
    o0.x = (float)a[0] + (float)b[0];
    o0.y = (float)a[1] + (float)b[1];
    o0.z = (float)a[2] + (float)b[2];
    o0.w = (float)a[3] + (float)b[3];
    o1.x = (float)a[4] + (float)b[4];
    o1.y = (float)a[5] + (float)b[5];
    o1.z = (float)a[6] + (float)b[6];
    o1.w = (float)a[7] + (float)b[7];
    *(float4*)(out + (size_t)t * DHID + c)     = o0;
    *(float4*)(out + (size_t)t * DHID + c + 4) = o1;
}

extern "C" void kernel_launch(void* const* d_in, const int* in_sizes, int n_in,
                              void* d_out, int out_size, void* d_ws, size_t ws_size,
                              hipStream_t stream)
{
    (void)in_sizes; (void)n_in; (void)out_size;
    const float* x  = (const float*)d_in[0];
    const float* wr = (const float*)d_in[1];
    const float* w1 = (const float*)d_in[2];
    const float* v1 = (const float*)d_in[3];
    const float* w2 = (const float*)d_in[4];
    float* out = (float*)d_out;

    char* ws = (char*)d_ws;
    size_t off = 0;
    auto alloc = [&](size_t bytes) -> void* {
        void* p = ws + off;
        off += bytes;
        off = (off + 255) & ~(size_t)255;
        return p;
    };
    __bf16* xb      = (__bf16*)alloc((size_t)T_TOK * DHID * 2);
    __bf16* H       = (__bf16*)alloc((size_t)NSLOT * IDIM * 2);
    __bf16* outslot = (__bf16*)alloc((size_t)NSLOT * DHID * 2);
    int*    topi    = (int*)  alloc((size_t)T_TOK * 2 * 4);
    float*  topg    = (float*)alloc((size_t)T_TOK * 2 * 4);
    int*    tok_of_slot  = (int*)  alloc((size_t)NSLOT * 4);
    float*  gate_of_slot = (float*)alloc((size_t)NSLOT * 4);
    int*    slot_of = (int*)  alloc((size_t)NSLOT * 4);
    int*    cnt     = (int*)  alloc(NEXP * 4);
    int*    basep   = (int*)  alloc(NEXP * 4);
    int*    fill    = (int*)  alloc(NEXP * 4);

    const size_t WELEMS = (size_t)NEXP * IDIM * DHID;      // 67.1M elems per weight tensor
    size_t base_need = off;
    bool bf16path = (ws_size >= base_need + 2 * WELEMS * 2 + (32 << 20));

    hipMemsetAsync(cnt, 0, NEXP * 4, stream);
    router_kernel<<<T_TOK / 4, 256, 0, stream>>>(x, wr, xb, topi, topg, cnt);
    scan_kernel<<<1, 64, 0, stream>>>(cnt, basep, fill);
    assign_kernel<<<T_TOK / 256, 256, 0, stream>>>(topi, topg, basep, fill,
                                                   tok_of_slot, gate_of_slot, slot_of);
    if (bf16path) {
        __bf16* wb1 = (__bf16*)alloc(WELEMS * 2);
        __bf16* wv1 = (__bf16*)alloc(WELEMS * 2);
        __bf16* wb2 = wb1;   // aliased: w2 converted AFTER proj into wb1's space
        convert_kernel<<<2048, 256, 0, stream>>>(w1, wb1, WELEMS / 8);
        convert_kernel<<<2048, 256, 0, stream>>>(v1, wv1, WELEMS / 8);
        moe_gemm<1, DHID, true><<<dim3(IDIM / 128, T_TOK / BM, NEXP), 256, 0, stream>>>(
            xb, wb1, wv1, tok_of_slot, gate_of_slot, cnt, basep, H);
        convert_kernel<<<2048, 256, 0, stream>>>(w2, wb2, WELEMS / 8);
        moe_gemm<2, IDIM, true><<<dim3(DHID / 256, T_TOK / BM, NEXP), 256, 0, stream>>>(
            H, wb2, nullptr, tok_of_slot, gate_of_slot, cnt, basep, outslot);
    } else {
        moe_gemm<1, DHID, false><<<dim3(IDIM / 128, T_TOK / BM, NEXP), 256, 0, stream>>>(
            xb, w1, v1, tok_of_slot, gate_of_slot, cnt, basep, H);
        moe_gemm<2, IDIM, false><<<dim3(DHID / 256, T_TOK / BM, NEXP), 256, 0, stream>>>(
            H, w2, nullptr, tok_of_slot, gate_of_slot, cnt, basep, outslot);
    }
    combine_kernel<<<(T_TOK * DHID / 8) / 256, 256, 0, stream>>>(outslot, slot_of, out);
}